// Round 9
// baseline (302.336 us; speedup 1.0000x reference)
//
#include <hip/hip_runtime.h>
#include <hip/hip_bf16.h>
#include <math.h>

#define DF 128
#define HID 256
#define NG 256

typedef __attribute__((ext_vector_type(8))) short s8v;    // 8 bf16 (4 VGPR)
typedef __attribute__((ext_vector_type(4))) float f32x4;  // MFMA acc

__device__ __forceinline__ float bf_lo(unsigned u){
  union{unsigned i; float f;} c; c.i = u<<16; return c.f;
}
__device__ __forceinline__ float bf_hi(unsigned u){
  union{unsigned i; float f;} c; c.i = u & 0xffff0000u; return c.f;
}
__device__ __forceinline__ unsigned pack2bf(float lo, float hi){
  unsigned a = __bfloat16_as_ushort(__float2bfloat16(lo));
  unsigned b = __bfloat16_as_ushort(__float2bfloat16(hi));
  return a | (b<<16);
}

// =============== binned CSR build (packed pairs: src<<9 | local_dst) ===============
__global__ void k_bhist(const int* __restrict__ dst, int* __restrict__ gb, int E){
  __shared__ int hist[256];
  int t = threadIdx.x;
  hist[t]=0; __syncthreads();
  for (int i = blockIdx.x*256+t; i < E; i += gridDim.x*256)
    atomicAdd(&hist[dst[i]>>9], 1);
  __syncthreads();
  if (hist[t]) atomicAdd(&gb[t], hist[t]);
}

__global__ void k_bscan(const int* __restrict__ gb, int* __restrict__ bbase,
                        int* __restrict__ bcur, int E){
  __shared__ int sh[256];
  int t = threadIdx.x;
  int v = gb[t];
  sh[t]=v; __syncthreads();
  for (int o=1;o<256;o<<=1){
    int x = (t>=o)? sh[t-o] : 0;
    __syncthreads();
    sh[t]+=x;
    __syncthreads();
  }
  int ex = sh[t]-v;
  bbase[t]=ex; bcur[t]=ex;
  if (t==255) bbase[256]=E;
}

__global__ __launch_bounds__(256)
void k_bplace(const int* __restrict__ src, const int* __restrict__ dst,
              int* __restrict__ bcur, unsigned* __restrict__ pairs, int E){
  __shared__ int hist[256];
  __shared__ int base[256];
  __shared__ int cur[256];
  const int t = threadIdx.x;
  const int CH = (E + gridDim.x - 1)/gridDim.x;
  const int s = blockIdx.x*CH;
  int e = s+CH; if (e>E) e=E;
  if (s>=E) return;
  hist[t]=0; __syncthreads();
  for (int i=s+t; i<e; i+=256) atomicAdd(&hist[dst[i]>>9],1);
  __syncthreads();
  if (hist[t]){ base[t]=atomicAdd(&bcur[t],hist[t]); }
  cur[t]=0;
  __syncthreads();
  for (int i=s+t; i<e; i+=256){
    int d = dst[i];
    int bk = d>>9;
    int r = atomicAdd(&cur[bk],1);
    pairs[base[bk]+r] = ((unsigned)src[i]<<9) | (unsigned)(d & 511);
  }
}

__global__ __launch_bounds__(256)
void k_bcsr(const unsigned* __restrict__ pairs, const int* __restrict__ bbase,
            int* __restrict__ offs, int* __restrict__ csr, int N, int E){
  __shared__ int ncnt[512];
  __shared__ int noff[512];
  __shared__ int sh[256];
  const int t = threadIdx.x;
  const int b = blockIdx.x;
  const int nb0 = b<<9;
  const int s = bbase[b], e = bbase[b+1];
  ncnt[t]=0; ncnt[t+256]=0;
  __syncthreads();
  for (int i=s+t; i<e; i+=256) atomicAdd(&ncnt[pairs[i] & 511u], 1);
  __syncthreads();
  int v0 = ncnt[2*t], v1 = ncnt[2*t+1];
  int v = v0+v1;
  sh[t]=v; __syncthreads();
  for (int o=1;o<256;o<<=1){
    int x=(t>=o)?sh[t-o]:0;
    __syncthreads();
    sh[t]+=x;
    __syncthreads();
  }
  int ex = sh[t]-v;
  noff[2*t]=ex; noff[2*t+1]=ex+v0;
  __syncthreads();
  {
    int n0 = nb0 + t;
    if (n0 < N) offs[n0] = s + noff[t];
    int n1 = nb0 + t + 256;
    if (n1 < N) offs[n1] = s + noff[t+256];
    if (b == gridDim.x-1 && t==0) offs[N] = E;
  }
  ncnt[t]=0; ncnt[t+256]=0;
  __syncthreads();
  for (int i=s+t; i<e; i+=256){
    unsigned p = pairs[i];
    int d = p & 511u;
    int r = atomicAdd(&ncnt[d],1);
    csr[s + noff[d] + r] = (int)(p >> 9);
  }
}

// ---------------- graph-size histogram ----------------
__global__ void k_gcnt(const int* __restrict__ gid, float* __restrict__ gcnt, int N){
  __shared__ int hist[256];
  int t = threadIdx.x;
  hist[t]=0; __syncthreads();
  for (int i = blockIdx.x*256+t; i < N; i += gridDim.x*256)
    atomicAdd(&hist[gid[i]], 1);
  __syncthreads();
  if (hist[t]) atomicAdd(&gcnt[t], (float)hist[t]);
}

// ---------------- weight prep ----------------
__global__ void k_prepw(const float* __restrict__ ws0, const float* __restrict__ wn0,
                        const float* __restrict__ ws1, const float* __restrict__ wn1,
                        unsigned short* __restrict__ wt){
  int n = blockIdx.x & 127;
  int layer = blockIdx.x >> 7;
  int k = threadIdx.x;                 // 0..255
  const float* ws = layer? ws1 : ws0;
  const float* wn = layer? wn1 : wn0;
  float v = (k<128)? ws[k*DF+n] : wn[(k-128)*DF+n];
  wt[((size_t)layer*DF + n)*256 + k] = __bfloat16_as_ushort(__float2bfloat16(v));
}

// ---------------- embedding gather -> bf16 h ----------------
__global__ void k_embed(const int* __restrict__ feat, const float* __restrict__ emb,
                        unsigned* __restrict__ h4, int N){
  int idx = blockIdx.x*256+threadIdx.x; // 8-elem chunk
  int total = N*(DF/8);
  if (idx<total){
    int i = idx/(DF/8), c = idx%(DF/8);
    const float4* e4 = (const float4*)emb;
    size_t rb = (size_t)feat[i]*(DF/4);
    float4 v0 = e4[rb + c*2], v1 = e4[rb + c*2+1];
    uint4 o;
    o.x = pack2bf(v0.x,v0.y); o.y = pack2bf(v0.z,v0.w);
    o.z = pack2bf(v1.x,v1.y); o.w = pack2bf(v1.z,v1.w);
    ((uint4*)h4)[idx] = o;
  }
}

// ---------------- fused SAGE layer: bf16 gather-mean + MFMA GEMM ----------------
// 16 nodes/block, 16 threads/node (one uint4 chunk each): 4-edge unroll keeps
// 4 loads in flight with only 8 f32 accumulators -> no spill at 8 waves/SIMD.
// MODE 0: write h_out bf16.  MODE 1: fused per-graph pool.
template<int MODE>
__global__ __launch_bounds__(256,8)
void k_sage(const unsigned short* __restrict__ h_in,
            const int* __restrict__ offs, const int* __restrict__ csr,
            const unsigned short* __restrict__ wt,
            const float* __restrict__ bias,
            unsigned short* __restrict__ h_out,
            const int* __restrict__ gid, float* __restrict__ gsum, int N){
  __shared__ __align__(16) unsigned short s_ab[16*256];   // 8KB (A-tile / cbuf)
  __shared__ int s_gid[16];
  __shared__ float s_tmp[DF];
  const int t = threadIdx.x;
  const int node0 = blockIdx.x*16;
  const uint4* hin4 = (const uint4*)h_in;   // 16 uint4 per row

  if (MODE==1 && t<16) s_gid[t] = (node0+t<N)? gid[node0+t] : -1;

  const int nn = t>>4;      // node 0..15
  const int c  = t&15;      // uint4 chunk 0..15
  const int sw = (nn&7)<<4;

  // ---- self row chunk: one uint4 per thread into A-tile cols 0..127, swizzled
  {
    int node = node0+nn;
    uint4 q = make_uint4(0,0,0,0);
    if (node<N) q = hin4[(size_t)node*16 + c];
    *(uint4*)((char*)s_ab + ((nn*512 + c*16) ^ sw)) = q;
  }

  // ---- neighbor mean: 16 threads/node, 4-edge unroll, 8 f32 accumulators
  {
    const int node = node0+nn;
    float a[8];
    #pragma unroll
    for (int j=0;j<8;j++) a[j]=0.f;
    if (node<N){
      int e0=offs[node], e1=offs[node+1];
      int deg = e1-e0;
      if (deg>0){
        #define ACC8(q) { \
          a[0]+=bf_lo(q.x); a[1]+=bf_hi(q.x); a[2]+=bf_lo(q.y); a[3]+=bf_hi(q.y); \
          a[4]+=bf_lo(q.z); a[5]+=bf_hi(q.z); a[6]+=bf_lo(q.w); a[7]+=bf_hi(q.w); }
        int e=e0;
        for (; e+4<=e1; e+=4){
          int s0=csr[e], s1=csr[e+1], s2=csr[e+2], s3=csr[e+3];
          uint4 q0 = hin4[(size_t)s0*16 + c];
          uint4 q1 = hin4[(size_t)s1*16 + c];
          uint4 q2 = hin4[(size_t)s2*16 + c];
          uint4 q3 = hin4[(size_t)s3*16 + c];
          ACC8(q0); ACC8(q1); ACC8(q2); ACC8(q3);
        }
        for (; e<e1; ++e){
          uint4 q0 = hin4[(size_t)csr[e]*16 + c];
          ACC8(q0);
        }
        #undef ACC8
        float inv = 1.0f/(float)deg;
        #pragma unroll
        for (int j=0;j<8;j++) a[j]*=inv;
      }
    }
    uint4 pk;
    pk.x = pack2bf(a[0],a[1]); pk.y = pack2bf(a[2],a[3]);
    pk.z = pack2bf(a[4],a[5]); pk.w = pack2bf(a[6],a[7]);
    *(uint4*)((char*)s_ab + ((nn*512 + 256 + c*16) ^ sw)) = pk;
  }

  const int wv = t>>6;
  const int lr = t&15;
  const int kg = (t&63)>>4;
  __syncthreads();

  // ---- MFMA main loop (M=16): wave wv covers n-cols [wv*32, wv*32+32)
  f32x4 acc0={0,0,0,0}, acc1={0,0,0,0};
  const s8v* wt8 = (const s8v*)wt;
  #pragma unroll
  for (int kh=0; kh<2; kh++){
    s8v bfrag[2][4];
    #pragma unroll
    for (int ks=0; ks<4; ks++){
      int kb = (kh*4+ks)*4 + kg;
      bfrag[0][ks] = wt8[(size_t)(wv*32     + lr)*32 + kb];
      bfrag[1][ks] = wt8[(size_t)(wv*32 + 16+ lr)*32 + kb];
    }
    #pragma unroll
    for (int ks=0; ks<4; ks++){
      int cb = (kh*4+ks)*64 + kg*16;
      s8v a0 = *(const s8v*)((const char*)s_ab + ((lr*512+cb) ^ ((lr&7)<<4)));
      acc0 = __builtin_amdgcn_mfma_f32_16x16x32_bf16(a0, bfrag[0][ks], acc0, 0,0,0);
      acc1 = __builtin_amdgcn_mfma_f32_16x16x32_bf16(a0, bfrag[1][ks], acc1, 0,0,0);
    }
  }
  __syncthreads();

  // ---- epilogue: acc -> LDS f32 [16][128]
  float* cbuf = (float*)s_ab;   // 8KB
  #pragma unroll
  for (int r=0;r<4;r++){
    int row0 = kg*4 + r;
    cbuf[row0*DF + wv*32      + lr] = acc0[r];
    cbuf[row0*DF + wv*32 + 16 + lr] = acc1[r];
  }
  __syncthreads();

  if (MODE==0){
    int row = t>>4, c0 = (t&15)*8;
    int node = node0+row;
    if (node<N){
      uint4 pk;
      float x0,x1;
      x0 = fmaxf(cbuf[row*DF+c0+0]+bias[c0+0],0.f); x1 = fmaxf(cbuf[row*DF+c0+1]+bias[c0+1],0.f);
      pk.x = pack2bf(x0,x1);
      x0 = fmaxf(cbuf[row*DF+c0+2]+bias[c0+2],0.f); x1 = fmaxf(cbuf[row*DF+c0+3]+bias[c0+3],0.f);
      pk.y = pack2bf(x0,x1);
      x0 = fmaxf(cbuf[row*DF+c0+4]+bias[c0+4],0.f); x1 = fmaxf(cbuf[row*DF+c0+5]+bias[c0+5],0.f);
      pk.z = pack2bf(x0,x1);
      x0 = fmaxf(cbuf[row*DF+c0+6]+bias[c0+6],0.f); x1 = fmaxf(cbuf[row*DF+c0+7]+bias[c0+7],0.f);
      pk.w = pack2bf(x0,x1);
      *(uint4*)&h_out[(size_t)node*DF + c0] = pk;
    }
  } else {
    // fused pool: segment loop over sorted gid runs; one atomic per (segment,d)
    const int d = t&127, rh = t>>7;
    const float bd = bias[d];
    int segStart = 0;
    while (segStart < 16 && s_gid[segStart] >= 0){
      int g = s_gid[segStart];
      int segEnd = segStart+1;
      while (segEnd < 16 && s_gid[segEnd] == g) segEnd++;
      float p = 0.f;
      for (int r = segStart+rh; r < segEnd; r += 2)
        p += fmaxf(cbuf[r*DF + d] + bd, 0.f);
      if (rh==1) s_tmp[d] = p;
      __syncthreads();
      if (rh==0) atomicAdd(&gsum[g*DF+d], p + s_tmp[d]);
      __syncthreads();
      segStart = segEnd;
    }
  }
}

// ---------------- fused MLP head ----------------
__global__ __launch_bounds__(256)
void k_head(const float* __restrict__ gsum, const float* __restrict__ gcnt,
            const float* __restrict__ e1w, const float* __restrict__ e1b,
            const float* __restrict__ e2w, const float* __restrict__ e2b,
            const float* __restrict__ e3w, const float* __restrict__ e3b,
            const float* __restrict__ e4w, const float* __restrict__ e4b,
            const float* __restrict__ pw,  const float* __restrict__ pb,
            float* __restrict__ out, float* __restrict__ hidden){
  __shared__ float hg[DF];
  __shared__ float bufA[HID];
  __shared__ float bufB[HID];
  __shared__ float r0[HID], r1[HID];
  const int g = blockIdx.x, t = threadIdx.x;
  if (t<DF) hg[t] = gsum[g*DF+t] / fmaxf(gcnt[g],1.0f);
  __syncthreads();

  float acc = e1b[t];
  for (int k=0;k<DF;++k) acc += hg[k]*e1w[k*HID+t];
  float h1 = fmaxf(acc,0.f);
  hidden[g*HID+t] = h1;
  bufA[t] = h1;
  __syncthreads();

  acc = e2b[t];
  for (int k=0;k<HID;++k) acc += bufA[k]*e2w[k*HID+t];
  bufB[t] = fmaxf(acc,0.f);
  __syncthreads();

  acc = e3b[t];
  for (int k=0;k<HID;++k) acc += bufB[k]*e3w[k*HID+t];
  bufA[t] = fmaxf(acc,0.f);
  __syncthreads();

  acc = e4b[t];
  for (int k=0;k<HID;++k) acc += bufA[k]*e4w[k*HID+t];
  float h4 = fmaxf(acc,0.f);

  r0[t] = h4*pw[t*2+0];
  r1[t] = h4*pw[t*2+1];
  __syncthreads();
  for (int o=128;o>0;o>>=1){
    if (t<o){ r0[t]+=r0[t+o]; r1[t]+=r1[t+o]; }
    __syncthreads();
  }
  if (t==0){
    float y0 = r0[0]+pb[0], y1 = r1[0]+pb[1];
    float m = fmaxf(y0,y1);
    float l = m + logf(expf(y0-m)+expf(y1-m));
    out[g*2+0]=y0-l;
    out[g*2+1]=y1-l;
  }
}

extern "C" void kernel_launch(void* const* d_in, const int* in_sizes, int n_in,
                              void* d_out, int out_size, void* d_ws, size_t ws_size,
                              hipStream_t stream){
  const int* feat = (const int*)d_in[0];
  const int* src  = (const int*)d_in[1];
  const int* dst  = (const int*)d_in[2];
  const int* gid  = (const int*)d_in[3];
  const float* emb = (const float*)d_in[4];
  const float* ws0 = (const float*)d_in[5];
  const float* wn0 = (const float*)d_in[6];
  const float* b0  = (const float*)d_in[7];
  const float* ws1 = (const float*)d_in[8];
  const float* wn1 = (const float*)d_in[9];
  const float* b1  = (const float*)d_in[10];
  const float* e1w = (const float*)d_in[11];
  const float* e1b = (const float*)d_in[12];
  const float* e2w = (const float*)d_in[13];
  const float* e2b = (const float*)d_in[14];
  const float* e3w = (const float*)d_in[15];
  const float* e3b = (const float*)d_in[16];
  const float* e4w = (const float*)d_in[17];
  const float* e4b = (const float*)d_in[18];
  const float* pw  = (const float*)d_in[19];
  const float* pb  = (const float*)d_in[20];
  const int N = in_sizes[0];
  const int E = in_sizes[1];

  char* basep = (char*)d_ws;
  size_t off=0;
  auto alloc=[&](size_t bytes)->void*{
    void* p = basep+off; off=(off+bytes+255)&~(size_t)255; return p;
  };
  unsigned short* hA = (unsigned short*)alloc((size_t)N*DF*2);
  unsigned short* hB = (unsigned short*)alloc((size_t)N*DF*2);
  int*   offs  = (int*)  alloc((size_t)(N+1)*4);
  int*   csr   = (int*)  alloc((size_t)E*4);
  int*   gb    = (int*)  alloc(1024);
  int*   bbase = (int*)  alloc(1056);   // 257 ints
  int*   bcur  = (int*)  alloc(1024);
  unsigned short* wtb = (unsigned short*)alloc((size_t)2*DF*256*2);
  float* gsum  = (float*)alloc((size_t)NG*DF*4);
  float* gcnt  = (float*)alloc((size_t)NG*4);
  // pairs aliases hB: consumed by k_bcsr strictly before layer-1 writes hB
  unsigned* pairs = (unsigned*)hB;
  float* out    = (float*)d_out;
  float* hidden = out + NG*2;

  hipMemsetAsync(gb, 0, 1024, stream);
  hipMemsetAsync(gsum, 0, (size_t)NG*DF*4, stream);
  hipMemsetAsync(gcnt, 0, (size_t)NG*4, stream);

  const int NBK = (N+511)>>9;
  k_bhist<<<256,256,0,stream>>>(dst,gb,E);
  k_bscan<<<1,256,0,stream>>>(gb,bbase,bcur,E);
  k_bplace<<<256,256,0,stream>>>(src,dst,bcur,pairs,E);
  k_bcsr<<<NBK,256,0,stream>>>(pairs,bbase,offs,csr,N,E);
  k_prepw<<<256,256,0,stream>>>(ws0,wn0,ws1,wn1,wtb);
  k_gcnt<<<256,256,0,stream>>>(gid,gcnt,N);

  k_embed<<<(N*(DF/8)+255)/256,256,0,stream>>>(feat,emb,(unsigned*)hA,N);
  k_sage<0><<<(N+15)/16,256,0,stream>>>(hA,offs,csr,wtb,        b0,hB,
                                        nullptr,nullptr,N);
  k_sage<1><<<(N+15)/16,256,0,stream>>>(hB,offs,csr,wtb+DF*256, b1,nullptr,
                                        gid,gsum,N);

  k_head<<<NG,HID,0,stream>>>(gsum,gcnt,e1w,e1b,e2w,e2b,e3w,e3b,e4w,e4b,
                              pw,pb,out,hidden);
}

// Round 10
// 228.941 us; speedup vs baseline: 1.3206x; 1.3206x over previous
//
#include <hip/hip_runtime.h>
#include <hip/hip_bf16.h>
#include <math.h>

#define DF 128
#define HID 256
#define NG 256

typedef __attribute__((ext_vector_type(8))) short s8v;    // 8 bf16 (4 VGPR)
typedef __attribute__((ext_vector_type(4))) float f32x4;  // MFMA acc
typedef __attribute__((ext_vector_type(2))) float f32x2;

__device__ __forceinline__ unsigned pack2bf(float lo, float hi){
  unsigned a = __bfloat16_as_ushort(__float2bfloat16(lo));
  unsigned b = __bfloat16_as_ushort(__float2bfloat16(hi));
  return a | (b<<16);
}

// =============== mega preprocessing kernel ===============
// blocks [0,NE): embed f32->bf16+fp8 ; [NE,NE+256): dst bucket hist ;
// [NE+256,NE+512): gid hist ; [NE+512,NE+768): weight transpose+cast.
__global__ __launch_bounds__(256)
void k_pre(const int* __restrict__ feat, const float* __restrict__ emb,
           unsigned* __restrict__ h_bf, unsigned* __restrict__ h_f8,
           const int* __restrict__ dst, int* __restrict__ gb,
           const int* __restrict__ gid, float* __restrict__ gcnt,
           const float* __restrict__ ws0, const float* __restrict__ wn0,
           const float* __restrict__ ws1, const float* __restrict__ wn1,
           unsigned short* __restrict__ wt,
           int N, int E, int NE){
  __shared__ int hist[256];
  const int b = blockIdx.x, t = threadIdx.x;
  if (b < NE){
    int idx = b*256 + t;                 // 8-elem chunk index
    int total = N*(DF/8);
    if (idx<total){
      int i = idx/(DF/8), c = idx%(DF/8);
      const float4* e4 = (const float4*)emb;
      size_t rb = (size_t)feat[i]*(DF/4);
      float4 v0 = e4[rb + c*2], v1 = e4[rb + c*2+1];
      uint4 o;
      o.x = pack2bf(v0.x,v0.y); o.y = pack2bf(v0.z,v0.w);
      o.z = pack2bf(v1.x,v1.y); o.w = pack2bf(v1.z,v1.w);
      ((uint4*)h_bf)[idx] = o;
      unsigned w0 = __builtin_amdgcn_cvt_pk_fp8_f32(v0.x, v0.y, 0, false);
      w0 = __builtin_amdgcn_cvt_pk_fp8_f32(v0.z, v0.w, w0, true);
      unsigned w1 = __builtin_amdgcn_cvt_pk_fp8_f32(v1.x, v1.y, 0, false);
      w1 = __builtin_amdgcn_cvt_pk_fp8_f32(v1.z, v1.w, w1, true);
      ((uint2*)h_f8)[idx] = make_uint2(w0,w1);
    }
  } else if (b < NE+256){
    int bb = b - NE;
    hist[t]=0; __syncthreads();
    for (int i = bb*256+t; i < E; i += 256*256)
      atomicAdd(&hist[dst[i]>>9], 1);
    __syncthreads();
    if (hist[t]) atomicAdd(&gb[t], hist[t]);
  } else if (b < NE+512){
    int bb = b - (NE+256);
    hist[t]=0; __syncthreads();
    for (int i = bb*256+t; i < N; i += 256*256)
      atomicAdd(&hist[gid[i]], 1);
    __syncthreads();
    if (hist[t]) atomicAdd(&gcnt[t], (float)hist[t]);
  } else {
    int bb = b - (NE+512);
    int n = bb & 127;
    int layer = bb >> 7;
    const float* ws = layer? ws1 : ws0;
    const float* wn = layer? wn1 : wn0;
    float v = (t<128)? ws[t*DF+n] : wn[(t-128)*DF+n];
    wt[((size_t)layer*DF + n)*256 + t] = __bfloat16_as_ushort(__float2bfloat16(v));
  }
}

// =============== binned CSR build (packed pairs: src<<9 | local_dst) ===============
__global__ void k_bscan(const int* __restrict__ gb, int* __restrict__ bbase,
                        int* __restrict__ bcur, int E){
  __shared__ int sh[256];
  int t = threadIdx.x;
  int v = gb[t];
  sh[t]=v; __syncthreads();
  for (int o=1;o<256;o<<=1){
    int x = (t>=o)? sh[t-o] : 0;
    __syncthreads();
    sh[t]+=x;
    __syncthreads();
  }
  int ex = sh[t]-v;
  bbase[t]=ex; bcur[t]=ex;
  if (t==255) bbase[256]=E;
}

__global__ __launch_bounds__(256)
void k_bplace(const int* __restrict__ src, const int* __restrict__ dst,
              int* __restrict__ bcur, unsigned* __restrict__ pairs, int E){
  __shared__ int hist[256];
  __shared__ int base[256];
  __shared__ int cur[256];
  const int t = threadIdx.x;
  const int CH = (E + gridDim.x - 1)/gridDim.x;
  const int s = blockIdx.x*CH;
  int e = s+CH; if (e>E) e=E;
  if (s>=E) return;
  hist[t]=0; __syncthreads();
  for (int i=s+t; i<e; i+=256) atomicAdd(&hist[dst[i]>>9],1);
  __syncthreads();
  if (hist[t]){ base[t]=atomicAdd(&bcur[t],hist[t]); }
  cur[t]=0;
  __syncthreads();
  for (int i=s+t; i<e; i+=256){
    int d = dst[i];
    int bk = d>>9;
    int r = atomicAdd(&cur[bk],1);
    pairs[base[bk]+r] = ((unsigned)src[i]<<9) | (unsigned)(d & 511);
  }
}

__global__ __launch_bounds__(256)
void k_bcsr(const unsigned* __restrict__ pairs, const int* __restrict__ bbase,
            int* __restrict__ offs, int* __restrict__ csr, int N, int E){
  __shared__ int ncnt[512];
  __shared__ int noff[512];
  __shared__ int sh[256];
  const int t = threadIdx.x;
  const int b = blockIdx.x;
  const int nb0 = b<<9;
  const int s = bbase[b], e = bbase[b+1];
  ncnt[t]=0; ncnt[t+256]=0;
  __syncthreads();
  for (int i=s+t; i<e; i+=256) atomicAdd(&ncnt[pairs[i] & 511u], 1);
  __syncthreads();
  int v0 = ncnt[2*t], v1 = ncnt[2*t+1];
  int v = v0+v1;
  sh[t]=v; __syncthreads();
  for (int o=1;o<256;o<<=1){
    int x=(t>=o)?sh[t-o]:0;
    __syncthreads();
    sh[t]+=x;
    __syncthreads();
  }
  int ex = sh[t]-v;
  noff[2*t]=ex; noff[2*t+1]=ex+v0;
  __syncthreads();
  {
    int n0 = nb0 + t;
    if (n0 < N) offs[n0] = s + noff[t];
    int n1 = nb0 + t + 256;
    if (n1 < N) offs[n1] = s + noff[t+256];
    if (b == gridDim.x-1 && t==0) offs[N] = E;
  }
  ncnt[t]=0; ncnt[t+256]=0;
  __syncthreads();
  for (int i=s+t; i<e; i+=256){
    unsigned p = pairs[i];
    int d = p & 511u;
    int r = atomicAdd(&ncnt[d],1);
    csr[s + noff[d] + r] = (int)(p >> 9);
  }
}

// ---------------- fused SAGE layer: fp8 gather-mean + MFMA GEMM ----------------
// R8-proven structure: 32 nodes/block, 8 thr/node, 2-edge unroll, bounds (256,6).
// Lane-loads/edge cut 24->12: fp8 rows (8 row-loads) + int2-paired csr (4 idx).
// MODE 0: write h_out bf16+fp8.  MODE 1: fused per-graph pool.
template<int MODE>
__global__ __launch_bounds__(256,6)
void k_sage(const unsigned short* __restrict__ h_in_bf,
            const unsigned char* __restrict__ h_in_f8,
            const int* __restrict__ offs, const int* __restrict__ csr,
            const unsigned short* __restrict__ wt,
            const float* __restrict__ bias,
            unsigned short* __restrict__ h_out_bf,
            unsigned char* __restrict__ h_out_f8,
            const int* __restrict__ gid, float* __restrict__ gsum, int N){
  __shared__ __align__(16) unsigned short s_ab[32*256];   // 16KB
  __shared__ int s_gid[32];
  __shared__ float s_tmp[DF];
  const int t = threadIdx.x;
  const int node0 = blockIdx.x*32;
  const uint4* hin4 = (const uint4*)h_in_bf;   // 16 uint4 per bf16 row
  const uint4* f8r  = (const uint4*)h_in_f8;   // 8 uint4 per fp8 row

  if (MODE==1 && t<32) s_gid[t] = (node0+t<N)? gid[node0+t] : -1;

  // ---- self rows: bf16 copy into A-tile cols 0..127, swizzled
  for (int idx = t; idx < 512; idx += 256){
    int nn = idx>>4, c = idx&15;
    int node = node0+nn;
    uint4 q = make_uint4(0,0,0,0);
    if (node<N) q = hin4[(size_t)node*16 + c];
    int byte = (nn*512 + c*16) ^ ((nn&7)<<4);
    *(uint4*)((char*)s_ab + byte) = q;
  }

  // ---- neighbor mean from fp8 rows: 8 thr/node, 16 cols/thr, 2-edge unroll,
  //      int2-paired index loads
  {
    const int nn = t>>3, c = t&7;
    const int node = node0+nn;
    float a[16];
    #pragma unroll
    for (int j=0;j<16;j++) a[j]=0.f;
    if (node<N){
      int e0=offs[node], e1=offs[node+1];
      int deg = e1-e0;
      if (deg>0){
        #define ACC16(q) { \
          f32x2 u; \
          u=__builtin_amdgcn_cvt_pk_f32_fp8((q).x,false); a[0]+=u[0]; a[1]+=u[1]; \
          u=__builtin_amdgcn_cvt_pk_f32_fp8((q).x,true ); a[2]+=u[0]; a[3]+=u[1]; \
          u=__builtin_amdgcn_cvt_pk_f32_fp8((q).y,false); a[4]+=u[0]; a[5]+=u[1]; \
          u=__builtin_amdgcn_cvt_pk_f32_fp8((q).y,true ); a[6]+=u[0]; a[7]+=u[1]; \
          u=__builtin_amdgcn_cvt_pk_f32_fp8((q).z,false); a[8]+=u[0]; a[9]+=u[1]; \
          u=__builtin_amdgcn_cvt_pk_f32_fp8((q).z,true ); a[10]+=u[0]; a[11]+=u[1]; \
          u=__builtin_amdgcn_cvt_pk_f32_fp8((q).w,false); a[12]+=u[0]; a[13]+=u[1]; \
          u=__builtin_amdgcn_cvt_pk_f32_fp8((q).w,true ); a[14]+=u[0]; a[15]+=u[1]; }
        int e = e0;
        if (e & 1){                       // align to even for int2 pairs
          uint4 q0 = f8r[(size_t)csr[e]*8 + c];
          ACC16(q0);
          e++;
        }
        for (; e+2<=e1; e+=2){
          int2 ss = *(const int2*)&csr[e];
          uint4 q0 = f8r[(size_t)ss.x*8 + c];
          uint4 q1 = f8r[(size_t)ss.y*8 + c];
          ACC16(q0); ACC16(q1);
        }
        if (e<e1){
          uint4 q0 = f8r[(size_t)csr[e]*8 + c];
          ACC16(q0);
        }
        #undef ACC16
        float inv = 1.0f/(float)deg;
        #pragma unroll
        for (int j=0;j<16;j++) a[j]*=inv;
      }
    }
    unsigned pk[8];
    #pragma unroll
    for (int j=0;j<8;j++) pk[j] = pack2bf(a[2*j],a[2*j+1]);
    int byte0 = nn*512 + 256 + c*32;
    int sw = (nn&7)<<4;
    *(uint4*)((char*)s_ab + ((byte0   )^sw)) = make_uint4(pk[0],pk[1],pk[2],pk[3]);
    *(uint4*)((char*)s_ab + ((byte0+16)^sw)) = make_uint4(pk[4],pk[5],pk[6],pk[7]);
  }

  const int wv = t>>6;
  const int lr = t&15;
  const int kg = (t&63)>>4;
  __syncthreads();

  // ---- MFMA main loop, B loaded per K-half from global (L2-resident)
  f32x4 acc00={0,0,0,0}, acc01={0,0,0,0}, acc10={0,0,0,0}, acc11={0,0,0,0};
  const s8v* wt8 = (const s8v*)wt;
  #pragma unroll
  for (int kh=0; kh<2; kh++){
    s8v bfrag[2][4];
    #pragma unroll
    for (int ks=0; ks<4; ks++){
      int kb = (kh*4+ks)*4 + kg;
      bfrag[0][ks] = wt8[(size_t)(wv*32     + lr)*32 + kb];
      bfrag[1][ks] = wt8[(size_t)(wv*32 + 16+ lr)*32 + kb];
    }
    #pragma unroll
    for (int ks=0; ks<4; ks++){
      int cb = (kh*4+ks)*64 + kg*16;
      int r0 = lr, r1 = 16+lr;
      s8v a0 = *(const s8v*)((const char*)s_ab + ((r0*512+cb) ^ ((r0&7)<<4)));
      s8v a1 = *(const s8v*)((const char*)s_ab + ((r1*512+cb) ^ ((r1&7)<<4)));
      acc00 = __builtin_amdgcn_mfma_f32_16x16x32_bf16(a0, bfrag[0][ks], acc00, 0,0,0);
      acc01 = __builtin_amdgcn_mfma_f32_16x16x32_bf16(a0, bfrag[1][ks], acc01, 0,0,0);
      acc10 = __builtin_amdgcn_mfma_f32_16x16x32_bf16(a1, bfrag[0][ks], acc10, 0,0,0);
      acc11 = __builtin_amdgcn_mfma_f32_16x16x32_bf16(a1, bfrag[1][ks], acc11, 0,0,0);
    }
  }
  __syncthreads();

  // ---- epilogue: acc -> LDS f32 [32][128]
  float* cbuf = (float*)s_ab;
  #pragma unroll
  for (int r=0;r<4;r++){
    int row0 = kg*4 + r;
    cbuf[(row0   )*DF + wv*32      + lr] = acc00[r];
    cbuf[(row0   )*DF + wv*32 + 16 + lr] = acc01[r];
    cbuf[(row0+16)*DF + wv*32      + lr] = acc10[r];
    cbuf[(row0+16)*DF + wv*32 + 16 + lr] = acc11[r];
  }
  __syncthreads();

  if (MODE==0){
    int row = t>>3, c0 = (t&7)*16;
    int node = node0+row;
    if (node<N){
      float x[16];
      #pragma unroll
      for (int j=0;j<16;j++) x[j] = fmaxf(cbuf[row*DF + c0 + j] + bias[c0+j], 0.f);
      unsigned pk[8];
      #pragma unroll
      for (int j=0;j<8;j++) pk[j] = pack2bf(x[2*j],x[2*j+1]);
      uint4* dstp = (uint4*)&h_out_bf[(size_t)node*DF + c0];
      dstp[0] = make_uint4(pk[0],pk[1],pk[2],pk[3]);
      dstp[1] = make_uint4(pk[4],pk[5],pk[6],pk[7]);
      unsigned f0 = __builtin_amdgcn_cvt_pk_fp8_f32(x[0], x[1], 0, false);
      f0 = __builtin_amdgcn_cvt_pk_fp8_f32(x[2], x[3], f0, true);
      unsigned f1 = __builtin_amdgcn_cvt_pk_fp8_f32(x[4], x[5], 0, false);
      f1 = __builtin_amdgcn_cvt_pk_fp8_f32(x[6], x[7], f1, true);
      unsigned f2 = __builtin_amdgcn_cvt_pk_fp8_f32(x[8], x[9], 0, false);
      f2 = __builtin_amdgcn_cvt_pk_fp8_f32(x[10], x[11], f2, true);
      unsigned f3 = __builtin_amdgcn_cvt_pk_fp8_f32(x[12], x[13], 0, false);
      f3 = __builtin_amdgcn_cvt_pk_fp8_f32(x[14], x[15], f3, true);
      *(uint4*)&h_out_f8[(size_t)node*DF + c0] = make_uint4(f0,f1,f2,f3);
    }
  } else {
    // fused pool: segment loop over sorted gid runs; one atomic per (segment,d)
    const int d = t&127, rh = t>>7;
    const float bd = bias[d];
    int segStart = 0;
    while (segStart < 32 && s_gid[segStart] >= 0){
      int g = s_gid[segStart];
      int segEnd = segStart+1;
      while (segEnd < 32 && s_gid[segEnd] == g) segEnd++;
      float p = 0.f;
      for (int r = segStart+rh; r < segEnd; r += 2)
        p += fmaxf(cbuf[r*DF + d] + bd, 0.f);
      if (rh==1) s_tmp[d] = p;
      __syncthreads();
      if (rh==0) atomicAdd(&gsum[g*DF+d], p + s_tmp[d]);
      __syncthreads();
      segStart = segEnd;
    }
  }
}

// ---------------- fused MLP head ----------------
__global__ __launch_bounds__(256)
void k_head(const float* __restrict__ gsum, const float* __restrict__ gcnt,
            const float* __restrict__ e1w, const float* __restrict__ e1b,
            const float* __restrict__ e2w, const float* __restrict__ e2b,
            const float* __restrict__ e3w, const float* __restrict__ e3b,
            const float* __restrict__ e4w, const float* __restrict__ e4b,
            const float* __restrict__ pw,  const float* __restrict__ pb,
            float* __restrict__ out, float* __restrict__ hidden){
  __shared__ float hg[DF];
  __shared__ float bufA[HID];
  __shared__ float bufB[HID];
  __shared__ float r0[HID], r1[HID];
  const int g = blockIdx.x, t = threadIdx.x;
  if (t<DF) hg[t] = gsum[g*DF+t] / fmaxf(gcnt[g],1.0f);
  __syncthreads();

  float acc = e1b[t];
  for (int k=0;k<DF;++k) acc += hg[k]*e1w[k*HID+t];
  float h1 = fmaxf(acc,0.f);
  hidden[g*HID+t] = h1;
  bufA[t] = h1;
  __syncthreads();

  acc = e2b[t];
  for (int k=0;k<HID;++k) acc += bufA[k]*e2w[k*HID+t];
  bufB[t] = fmaxf(acc,0.f);
  __syncthreads();

  acc = e3b[t];
  for (int k=0;k<HID;++k) acc += bufB[k]*e3w[k*HID+t];
  bufA[t] = fmaxf(acc,0.f);
  __syncthreads();

  acc = e4b[t];
  for (int k=0;k<HID;++k) acc += bufA[k]*e4w[k*HID+t];
  float h4 = fmaxf(acc,0.f);

  r0[t] = h4*pw[t*2+0];
  r1[t] = h4*pw[t*2+1];
  __syncthreads();
  for (int o=128;o>0;o>>=1){
    if (t<o){ r0[t]+=r0[t+o]; r1[t]+=r1[t+o]; }
    __syncthreads();
  }
  if (t==0){
    float y0 = r0[0]+pb[0], y1 = r1[0]+pb[1];
    float m = fmaxf(y0,y1);
    float l = m + logf(expf(y0-m)+expf(y1-m));
    out[g*2+0]=y0-l;
    out[g*2+1]=y1-l;
  }
}

extern "C" void kernel_launch(void* const* d_in, const int* in_sizes, int n_in,
                              void* d_out, int out_size, void* d_ws, size_t ws_size,
                              hipStream_t stream){
  const int* feat = (const int*)d_in[0];
  const int* src  = (const int*)d_in[1];
  const int* dst  = (const int*)d_in[2];
  const int* gid  = (const int*)d_in[3];
  const float* emb = (const float*)d_in[4];
  const float* ws0 = (const float*)d_in[5];
  const float* wn0 = (const float*)d_in[6];
  const float* b0  = (const float*)d_in[7];
  const float* ws1 = (const float*)d_in[8];
  const float* wn1 = (const float*)d_in[9];
  const float* b1  = (const float*)d_in[10];
  const float* e1w = (const float*)d_in[11];
  const float* e1b = (const float*)d_in[12];
  const float* e2w = (const float*)d_in[13];
  const float* e2b = (const float*)d_in[14];
  const float* e3w = (const float*)d_in[15];
  const float* e3b = (const float*)d_in[16];
  const float* e4w = (const float*)d_in[17];
  const float* e4b = (const float*)d_in[18];
  const float* pw  = (const float*)d_in[19];
  const float* pb  = (const float*)d_in[20];
  const int N = in_sizes[0];
  const int E = in_sizes[1];

  char* basep = (char*)d_ws;
  size_t off=0;
  auto alloc=[&](size_t bytes)->void*{
    void* p = basep+off; off=(off+bytes+255)&~(size_t)255; return p;
  };
  unsigned short* hA_bf = (unsigned short*)alloc((size_t)N*DF*2);
  unsigned char*  hA_f8 = (unsigned char*) alloc((size_t)N*DF);
  unsigned short* hB_bf = (unsigned short*)alloc((size_t)N*DF*2);
  unsigned char*  hB_f8 = (unsigned char*) alloc((size_t)N*DF);
  int*   offs  = (int*)  alloc((size_t)(N+1)*4);
  int*   csr   = (int*)  alloc((size_t)E*4);
  int*   gb    = (int*)  alloc(1024);
  int*   bbase = (int*)  alloc(1056);   // 257 ints
  int*   bcur  = (int*)  alloc(1024);
  unsigned short* wtb = (unsigned short*)alloc((size_t)2*DF*256*2);
  float* gsum  = (float*)alloc((size_t)NG*DF*4);
  float* gcnt  = (float*)alloc((size_t)NG*4);
  // pairs aliases hB_bf: consumed by k_bcsr strictly before layer-1 writes hB
  unsigned* pairs = (unsigned*)hB_bf;
  float* out    = (float*)d_out;
  float* hidden = out + NG*2;

  hipMemsetAsync(gb, 0, 1024, stream);
  hipMemsetAsync(gsum, 0, (size_t)NG*DF*4, stream);
  hipMemsetAsync(gcnt, 0, (size_t)NG*4, stream);

  const int NBK = (N+511)>>9;
  const int NE = (N*(DF/8) + 255)/256;
  k_pre<<<NE+768,256,0,stream>>>(feat,emb,(unsigned*)hA_bf,(unsigned*)hA_f8,
                                 dst,gb,gid,gcnt,
                                 ws0,wn0,ws1,wn1,wtb,N,E,NE);
  k_bscan<<<1,256,0,stream>>>(gb,bbase,bcur,E);
  k_bplace<<<256,256,0,stream>>>(src,dst,bcur,pairs,E);
  k_bcsr<<<NBK,256,0,stream>>>(pairs,bbase,offs,csr,N,E);

  k_sage<0><<<(N+31)/32,256,0,stream>>>(hA_bf,hA_f8,offs,csr,wtb,        b0,
                                        hB_bf,hB_f8,nullptr,nullptr,N);
  k_sage<1><<<(N+31)/32,256,0,stream>>>(hB_bf,hB_f8,offs,csr,wtb+DF*256, b1,
                                        nullptr,nullptr,gid,gsum,N);

  k_head<<<NG,HID,0,stream>>>(gsum,gcnt,e1w,e1b,e2w,e2b,e3w,e3b,e4w,e4b,
                              pw,pb,out,hidden);
}